// Round 3
// baseline (258.260 us; speedup 1.0000x reference)
//
#include <hip/hip_runtime.h>
#include <math.h>

#define B_N     16384
#define D_IN    784
#define D_HID   256
#define D_LAT   8
#define N_CTR   64
#define CH_N    64
#define N_CLS   10

#define DT_C    0.1f
#define EPS_C   1e-4f
#define PM_STEPS 4
#define TAU_C   0.9f
#define MGAIN   0.1f
#define EIG     0.06f
#define PLR_C   0.001f
#define T_STEPS 5

#define KP      832   // 784 padded to 13*64

typedef short bf16x8 __attribute__((ext_vector_type(8)));
typedef float f32x4v __attribute__((ext_vector_type(4)));

// split f32 pair -> packed bf16 hi word + lo word (truncation; lo captures residual)
__device__ __forceinline__ void split_pair(float a, float b, unsigned& hi, unsigned& lo) {
    unsigned ua = __float_as_uint(a), ub = __float_as_uint(b);
    hi = (ua >> 16) | (ub & 0xffff0000u);
    float ra = a - __uint_as_float(ua & 0xffff0000u);
    float rb = b - __uint_as_float(ub & 0xffff0000u);
    lo = (__float_as_uint(ra) >> 16) | (__float_as_uint(rb) & 0xffff0000u);
}

// ---------------- w1t: W1[784][256] f32 -> Wt_hi/Wt_lo[256][832] bf16 (zero-padded) ----------------
__global__ __launch_bounds__(256) void w1t_kernel(
    const float* __restrict__ W1, ushort* __restrict__ WtH, ushort* __restrict__ WtL)
{
    __shared__ float t[32][36];
    const int kb = blockIdx.x;          // 0..25
    const int nb = blockIdx.y;          // 0..7
    const int tid = threadIdx.x;
    {
        const int r = tid >> 3, c4 = (tid & 7) * 4;
        const int k = kb * 32 + r;
        float4 v = {0.f, 0.f, 0.f, 0.f};
        if (k < D_IN) v = *(const float4*)(W1 + (size_t)k * 256 + nb * 32 + c4);
        t[r][c4 + 0] = v.x; t[r][c4 + 1] = v.y; t[r][c4 + 2] = v.z; t[r][c4 + 3] = v.w;
    }
    __syncthreads();
    const int n = tid >> 3, kq = (tid & 7) * 4;
    float a0 = t[kq + 0][n], a1 = t[kq + 1][n], a2 = t[kq + 2][n], a3 = t[kq + 3][n];
    unsigned h0, l0, h1w, l1w;
    split_pair(a0, a1, h0, l0);
    split_pair(a2, a3, h1w, l1w);
    const size_t o = (size_t)(nb * 32 + n) * KP + kb * 32 + kq;
    uint2 hv; hv.x = h0; hv.y = h1w;
    uint2 lv; lv.x = l0; lv.y = l1w;
    *(uint2*)(WtH + o) = hv;
    *(uint2*)(WtL + o) = lv;
}

// ---------------- enc1: h1[B,256] = tanh(x @ W1 + b1), split-bf16 3-pass MFMA ----------------
// BM=128, BN=64, BK=64. 256 threads = 4 waves (2x2), wave-tile 64x32.
__global__ __launch_bounds__(256, 2) void enc1_kernel(
    const float* __restrict__ x, const ushort* __restrict__ WtH,
    const ushort* __restrict__ WtL, const float* __restrict__ b1,
    float* __restrict__ h1)
{
    __shared__ alignas(16) unsigned char AhiS[16384];
    __shared__ alignas(16) unsigned char AloS[16384];
    __shared__ alignas(16) unsigned char BhiS[8192];
    __shared__ alignas(16) unsigned char BloS[8192];

    const int tid = threadIdx.x;
    const int bx  = blockIdx.x;
    const int n0  = (bx & 3) * 64;
    const int m0  = (bx >> 2) * 128;

    // ---- staging maps ----
    const int m_s = tid >> 1, kh = tid & 1;          // A: row, k-half (32 k each)
    const int n_s = tid >> 2, kq = tid & 3;          // B: row, k-quarter (16 k each)
    const float*  xrow = x + (size_t)(m0 + m_s) * D_IN;
    const ushort* bhp  = WtH + (size_t)(n0 + n_s) * KP + kq * 16;
    const ushort* blp  = WtL + (size_t)(n0 + n_s) * KP + kq * 16;

    float4 aReg[8];
    uint4  bRegH[2], bRegL[2];

    // ---- compute maps ----
    const int lane = tid & 63;
    const int wid  = tid >> 6;
    const int wm   = wid >> 1, wn = wid & 1;
    const int fr   = lane & 15, g = lane >> 4;
    const unsigned swz = (unsigned)((fr & 7) << 4);
    const int kgb  = g * 16;

    f32x4v acc[4][2];
    #pragma unroll
    for (int mi = 0; mi < 4; ++mi)
        #pragma unroll
        for (int ni = 0; ni < 2; ++ni) acc[mi][ni] = (f32x4v){0.f, 0.f, 0.f, 0.f};

    // prologue loads for tile 0
    {
        const int kb0 = kh * 32;
        #pragma unroll
        for (int q = 0; q < 8; ++q) {
            const int kk = kb0 + q * 4;
            float4 z4 = {0.f, 0.f, 0.f, 0.f};
            aReg[q] = (kk < D_IN) ? *(const float4*)(xrow + kk) : z4;
        }
        bRegH[0] = *(const uint4*)(bhp);
        bRegH[1] = *(const uint4*)(bhp + 8);
        bRegL[0] = *(const uint4*)(blp);
        bRegL[1] = *(const uint4*)(blp + 8);
    }

    for (int kt = 0; kt < 13; ++kt) {
        // ---- convert + LDS write (tile kt) ----
        #pragma unroll
        for (int q16 = 0; q16 < 4; ++q16) {
            uint4 hw, lw;
            split_pair(aReg[2 * q16].x,     aReg[2 * q16].y,     hw.x, lw.x);
            split_pair(aReg[2 * q16].z,     aReg[2 * q16].w,     hw.y, lw.y);
            split_pair(aReg[2 * q16 + 1].x, aReg[2 * q16 + 1].y, hw.z, lw.z);
            split_pair(aReg[2 * q16 + 1].z, aReg[2 * q16 + 1].w, hw.w, lw.w);
            const unsigned off = (unsigned)(m_s * 128) +
                (((unsigned)(kh * 64 + q16 * 16)) ^ ((unsigned)((m_s & 7) << 4)));
            *(uint4*)(AhiS + off) = hw;
            *(uint4*)(AloS + off) = lw;
        }
        #pragma unroll
        for (int h = 0; h < 2; ++h) {
            const unsigned off = (unsigned)(n_s * 128) +
                (((unsigned)(kq * 32 + h * 16)) ^ ((unsigned)((n_s & 7) << 4)));
            *(uint4*)(BhiS + off) = bRegH[h];
            *(uint4*)(BloS + off) = bRegL[h];
        }
        __syncthreads();   // LDS tile ready

        // ---- issue next-tile global loads (hide latency under MFMA) ----
        if (kt < 12) {
            const int k0 = (kt + 1) * 64;
            const int kb0 = k0 + kh * 32;
            #pragma unroll
            for (int q = 0; q < 8; ++q) {
                const int kk = kb0 + q * 4;
                float4 z4 = {0.f, 0.f, 0.f, 0.f};
                aReg[q] = (kk < D_IN) ? *(const float4*)(xrow + kk) : z4;
            }
            bRegH[0] = *(const uint4*)(bhp + k0);
            bRegH[1] = *(const uint4*)(bhp + k0 + 8);
            bRegL[0] = *(const uint4*)(blp + k0);
            bRegL[1] = *(const uint4*)(blp + k0 + 8);
        }

        // ---- compute ----
        #pragma unroll
        for (int ks = 0; ks < 2; ++ks) {
            const unsigned kb = (unsigned)(ks * 64 + kgb);
            bf16x8 ah[4], al[4];
            #pragma unroll
            for (int mi = 0; mi < 4; ++mi) {
                const unsigned off = (unsigned)((wm * 64 + mi * 16 + fr) * 128) + (kb ^ swz);
                ah[mi] = *(const bf16x8*)(AhiS + off);
                al[mi] = *(const bf16x8*)(AloS + off);
            }
            #pragma unroll
            for (int ni = 0; ni < 2; ++ni) {
                const unsigned offb = (unsigned)((wn * 32 + ni * 16 + fr) * 128) + (kb ^ swz);
                bf16x8 bh = *(const bf16x8*)(BhiS + offb);
                bf16x8 bl = *(const bf16x8*)(BloS + offb);
                #pragma unroll
                for (int mi = 0; mi < 4; ++mi) {
                    acc[mi][ni] = __builtin_amdgcn_mfma_f32_16x16x32_bf16(ah[mi], bh, acc[mi][ni], 0, 0, 0);
                    acc[mi][ni] = __builtin_amdgcn_mfma_f32_16x16x32_bf16(ah[mi], bl, acc[mi][ni], 0, 0, 0);
                    acc[mi][ni] = __builtin_amdgcn_mfma_f32_16x16x32_bf16(al[mi], bh, acc[mi][ni], 0, 0, 0);
                }
            }
        }
        __syncthreads();   // all reads done before next tile's writes
    }

    // ---- epilogue: tanh(acc + b1) -> h1 ----
    #pragma unroll
    for (int ni = 0; ni < 2; ++ni) {
        const int col = n0 + wn * 32 + ni * 16 + fr;
        const float bias = b1[col];
        #pragma unroll
        for (int mi = 0; mi < 4; ++mi) {
            #pragma unroll
            for (int r = 0; r < 4; ++r) {
                const int row = m0 + wm * 64 + mi * 16 + g * 4 + r;
                h1[(size_t)row * 256 + col] = tanhf(acc[mi][ni][r] + bias);
            }
        }
    }
}

// ---------------- enc2: zT[b][d] = h1[b,:] @ W2[:,d] + b2[d] ----------------
__global__ __launch_bounds__(256) void enc2_kernel(
    const float* __restrict__ h1, const float* __restrict__ W2,
    const float* __restrict__ b2, float* __restrict__ zT)
{
    __shared__ alignas(16) float hs[32][260];
    __shared__ alignas(16) float w2t[8][260];
    const int tid = threadIdx.x;
    const int r0 = blockIdx.x * 32;
    for (int i = tid; i < D_HID * D_LAT; i += 256) {
        int k = i >> 3, d = i & 7;
        w2t[d][k] = W2[i];
    }
    #pragma unroll
    for (int i = 0; i < 8; ++i) {
        int idx = tid + i * 256;
        int rr = idx >> 6, c4 = idx & 63;
        float4 v = *(const float4*)(h1 + (size_t)(r0 + rr) * D_HID + c4 * 4);
        *(float4*)&hs[rr][c4 * 4] = v;
    }
    __syncthreads();
    const int r = tid >> 3, d = tid & 7;
    float acc = 0.f;
    #pragma unroll 8
    for (int k4 = 0; k4 < 64; ++k4) {
        float4 a = *(const float4*)&hs[r][k4 * 4];
        float4 w = *(const float4*)&w2t[d][k4 * 4];
        acc = fmaf(a.x, w.x, acc);
        acc = fmaf(a.y, w.y, acc);
        acc = fmaf(a.z, w.z, acc);
        acc = fmaf(a.w, w.w, acc);
    }
    zT[(size_t)(r0 + r) * 8 + d] = acc + b2[d];
}

// ---------------- stepA2: 8 lanes per batch element ----------------
__global__ __launch_bounds__(256) void stepA2_kernel(
    float* __restrict__ zT, float* __restrict__ hT,
    const float* __restrict__ mu, const float* __restrict__ c,
    const float* __restrict__ Wp, const float* __restrict__ bp,
    const float* __restrict__ Wr, const float* __restrict__ br,
    float* __restrict__ actT, float* __restrict__ postb,
    float* __restrict__ out, int t)
{
    __shared__ alignas(16) float mu_s[64];
    __shared__ alignas(16) float c_s[512];
    __shared__ alignas(16) float wp_s[512];
    __shared__ alignas(16) float bp_s[64];
    __shared__ alignas(16) float wr_s[704];
    __shared__ alignas(16) float br_s[16];
    const int tid = threadIdx.x;
    if (tid < 64) { mu_s[tid] = mu[tid]; bp_s[tid] = bp[tid]; }
    for (int i = tid; i < 512; i += 256) { c_s[i] = c[i]; wp_s[i] = Wp[i]; }
    const bool last = (t == T_STEPS - 1);
    if (last) {
        for (int i = tid; i < 640; i += 256) wr_s[(i / 10) * 11 + (i % 10)] = Wr[i];
        if (tid < N_CLS) br_s[tid] = br[tid];
    }
    __syncthreads();

    const int sub  = tid & 7;
    const int b    = blockIdx.x * 32 + (tid >> 3);
    const int lane = tid & 63;
    const int gbase = lane & ~7;

    float zown = zT[(size_t)b * 8 + sub];
    float z[8];
    #pragma unroll
    for (int d = 0; d < 8; ++d) z[d] = __shfl(zown, gbase + d, 64);

    #pragma unroll 1
    for (int it = 0; it < PM_STEPS; ++it) {
        float f[8];
        #pragma unroll
        for (int d = 0; d < 8; ++d) f[d] = 0.f;
        #pragma unroll
        for (int k = 0; k < 8; ++k) {
            const int n = sub + 8 * k;
            float dx[8];
            float r2 = EPS_C;
            #pragma unroll
            for (int d = 0; d < 8; ++d) {
                dx[d] = c_s[n * 8 + d] - z[d];
                r2 = fmaf(dx[d], dx[d], r2);
            }
            float w = mu_s[n] / r2;
            #pragma unroll
            for (int d = 0; d < 8; ++d) f[d] = fmaf(w, dx[d], f[d]);
        }
        #pragma unroll
        for (int m = 1; m <= 4; m <<= 1)
            #pragma unroll
            for (int d = 0; d < 8; ++d) f[d] += __shfl_xor(f[d], m, 64);
        #pragma unroll
        for (int d = 0; d < 8; ++d) z[d] = fmaf(DT_C, f[d], z[d]);
    }
    float zsel = z[0];
    #pragma unroll
    for (int d = 1; d < 8; ++d) if (sub == d) zsel = z[d];
    zT[(size_t)b * 8 + sub] = zsel;

    float hn[8];
    float s = 0.f;
    #pragma unroll
    for (int j = 0; j < 8; ++j) {
        const int ch = sub * 8 + j;
        float a = bp_s[ch];
        #pragma unroll
        for (int d = 0; d < 8; ++d) a = fmaf(z[d], wp_s[d * 64 + ch], a);
        hn[j] = tanhf(a);
    }
    if (t == 0) {
        #pragma unroll
        for (int j = 0; j < 8; ++j) { hn[j] = MGAIN * hn[j]; s += hn[j]; }
    } else {
        const float4* hp = (const float4*)(hT + (size_t)b * 64 + sub * 8);
        float4 h0 = hp[0], h1v = hp[1];
        hn[0] = TAU_C * h0.x + MGAIN * hn[0];
        hn[1] = TAU_C * h0.y + MGAIN * hn[1];
        hn[2] = TAU_C * h0.z + MGAIN * hn[2];
        hn[3] = TAU_C * h0.w + MGAIN * hn[3];
        hn[4] = TAU_C * h1v.x + MGAIN * hn[4];
        hn[5] = TAU_C * h1v.y + MGAIN * hn[5];
        hn[6] = TAU_C * h1v.z + MGAIN * hn[6];
        hn[7] = TAU_C * h1v.w + MGAIN * hn[7];
        #pragma unroll
        for (int j = 0; j < 8; ++j) s += hn[j];
    }
    #pragma unroll
    for (int m = 1; m <= 4; m <<= 1) s += __shfl_xor(s, m, 64);
    const float mean = s * (1.f / 64.f);
    float spost = 0.f;
    #pragma unroll
    for (int j = 0; j < 8; ++j) {
        hn[j] = hn[j] + EIG * (hn[j] - mean);
        spost += hn[j];
    }
    {
        float4 a0 = {hn[0], hn[1], hn[2], hn[3]};
        float4 a1 = {hn[4], hn[5], hn[6], hn[7]};
        float4* hp = (float4*)(hT + (size_t)b * 64 + sub * 8);
        hp[0] = a0; hp[1] = a1;
    }
    #pragma unroll
    for (int m = 1; m <= 4; m <<= 1) spost += __shfl_xor(spost, m, 64);

    if (!last) {
        if (sub == 0) postb[b] = spost * (1.f / 64.f);
        #pragma unroll
        for (int k = 0; k < 8; ++k) {
            const int n = sub + 8 * k;
            float r2 = 0.f;
            #pragma unroll
            for (int d = 0; d < 8; ++d) {
                float dd = c_s[n * 8 + d] - z[d];
                r2 = fmaf(dd, dd, r2);
            }
            actT[(size_t)b * 64 + n] = expf(-r2);
        }
    } else {
        float lg[N_CLS];
        #pragma unroll
        for (int cls = 0; cls < N_CLS; ++cls) lg[cls] = 0.f;
        #pragma unroll
        for (int j = 0; j < 8; ++j) {
            const int ch = sub * 8 + j;
            #pragma unroll
            for (int cls = 0; cls < N_CLS; ++cls)
                lg[cls] = fmaf(hn[j], wr_s[ch * 11 + cls], lg[cls]);
        }
        #pragma unroll
        for (int m = 1; m <= 4; m <<= 1)
            #pragma unroll
            for (int cls = 0; cls < N_CLS; ++cls) lg[cls] += __shfl_xor(lg[cls], m, 64);
        if (sub == 0) {
            #pragma unroll
            for (int cls = 0; cls < N_CLS; ++cls)
                out[(size_t)b * 10 + cls] = lg[cls] + br_s[cls];
        }
        out[163840 + (size_t)b * 8 + sub] = zsel;
        {
            float4 a0 = {hn[0], hn[1], hn[2], hn[3]};
            float4 a1 = {hn[4], hn[5], hn[6], hn[7]};
            float4* op = (float4*)(out + 294912 + (size_t)b * 64 + sub * 8);
            op[0] = a0; op[1] = a1;
        }
    }
}

// ---------------- stepB stage 1: per-chunk partial sums ----------------
__global__ __launch_bounds__(256) void stepB1_kernel(
    const float* __restrict__ actT, const float* __restrict__ postb,
    const float* __restrict__ zT, float* __restrict__ part)
{
    const int g = blockIdx.x, tid = threadIdx.x;
    const int n = tid & 63, q = tid >> 6;
    const int b0 = g * 64 + q * 16;
    float acc[10];
    #pragma unroll
    for (int j = 0; j < 10; ++j) acc[j] = 0.f;
    for (int i = 0; i < 16; ++i) {
        const int b = b0 + i;
        float a = actT[(size_t)b * 64 + n];
        float p = postb[b];
        acc[0] += a;
        acc[1] = fmaf(a, p, acc[1]);
        #pragma unroll
        for (int d = 0; d < 8; ++d)
            acc[2 + d] = fmaf(a, zT[(size_t)b * 8 + d], acc[2 + d]);
    }
    __shared__ float red[4][64][10];
    #pragma unroll
    for (int j = 0; j < 10; ++j) red[q][n][j] = acc[j];
    __syncthreads();
    if (q == 0) {
        #pragma unroll
        for (int j = 0; j < 10; ++j) {
            float sv = (red[0][n][j] + red[1][n][j]) + (red[2][n][j] + red[3][n][j]);
            part[(size_t)(g * 64 + n) * 10 + j] = sv;
        }
    }
}

// ---------------- stepB stage 2: final reduce + mu/c update ----------------
__global__ __launch_bounds__(256) void stepB2_kernel(
    const float* __restrict__ part,
    const float* __restrict__ mu_in, const float* __restrict__ c_in,
    float* __restrict__ mu_out, float* __restrict__ c_out)
{
    const int n = blockIdx.x, tid = threadIdx.x;
    __shared__ float red[256][10];
    const float* p = part + ((size_t)tid * 64 + n) * 10;
    #pragma unroll
    for (int j = 0; j < 10; ++j) red[tid][j] = p[j];
    __syncthreads();
    for (int s = 128; s > 0; s >>= 1) {
        if (tid < s) {
            #pragma unroll
            for (int j = 0; j < 10; ++j) red[tid][j] += red[tid + s][j];
        }
        __syncthreads();
    }
    if (tid == 0) {
        const float S1 = red[0][0];
        const float S2 = red[0][1] * (1.f / B_N);
        mu_out[n] = mu_in[n] + PLR_C * S2;
        const float denom = S1 + EPS_C;
        #pragma unroll
        for (int d = 0; d < 8; ++d) {
            float s3 = red[0][2 + d];
            c_out[n * 8 + d] = c_in[n * 8 + d] + PLR_C * (s3 / denom - c_in[n * 8 + d] * (S1 / denom));
        }
    }
}

extern "C" void kernel_launch(void* const* d_in, const int* in_sizes, int n_in,
                              void* d_out, int out_size, void* d_ws, size_t ws_size,
                              hipStream_t stream) {
    (void)in_sizes; (void)n_in; (void)out_size; (void)ws_size;
    const float* x   = (const float*)d_in[0];
    const float* W1  = (const float*)d_in[1];
    const float* b1  = (const float*)d_in[2];
    const float* W2  = (const float*)d_in[3];
    const float* b2  = (const float*)d_in[4];
    const float* mu0 = (const float*)d_in[5];
    const float* c0  = (const float*)d_in[6];
    const float* Wp  = (const float*)d_in[7];
    const float* bp  = (const float*)d_in[8];
    const float* Wr  = (const float*)d_in[9];
    const float* br  = (const float*)d_in[10];
    float* out = (float*)d_out;
    float* ws  = (float*)d_ws;

    // ws layout (floats). h1 (16 MB) dead after enc2; hT/actT/postb/part alias it.
    float* h1    = ws;                       // [B,256]    4,194,304
    float* hT    = ws;                       // [B][64]    1,048,576 (aliases h1)
    float* actT  = ws + 1048576;             // [B][64]    1,048,576 (aliases h1)
    float* postb = ws + 2097152;             // [B]           16,384 (aliases h1)
    float* part  = ws + 2113536;             // [256][64][10] 163,840 (aliases h1)
    float* zT    = ws + 4194304;             // [B][8]       131,072
    float* mu_buf = ws + 4325376;            // 2 x 64
    float* c_buf  = ws + 4325504;            // 2 x 512
    ushort* WtH  = (ushort*)(ws + 4326528);  // [256][832] bf16 = 106,496 floats
    ushort* WtL  = (ushort*)(ws + 4433024);  // [256][832] bf16

    w1t_kernel<<<dim3(26, 8), 256, 0, stream>>>(W1, WtH, WtL);
    enc1_kernel<<<512, 256, 0, stream>>>(x, WtH, WtL, b1, h1);
    enc2_kernel<<<512, 256, 0, stream>>>(h1, W2, b2, zT);

    const float* mu_cur = mu0;
    const float* c_cur  = c0;
    for (int t = 0; t < T_STEPS; ++t) {
        stepA2_kernel<<<512, 256, 0, stream>>>(zT, hT, mu_cur, c_cur, Wp, bp, Wr, br,
                                               actT, postb, out, t);
        if (t < T_STEPS - 1) {
            stepB1_kernel<<<256, 256, 0, stream>>>(actT, postb, zT, part);
            float* mo = mu_buf + (t & 1) * 64;
            float* co = c_buf  + (t & 1) * 512;
            stepB2_kernel<<<64, 256, 0, stream>>>(part, mu_cur, c_cur, mo, co);
            mu_cur = mo;
            c_cur  = co;
        }
    }
}

// Round 4
// 141.876 us; speedup vs baseline: 1.8203x; 1.8203x over previous
//
#include <hip/hip_runtime.h>
#include <math.h>

#define B_N     16384
#define D_IN    784
#define D_HID   256
#define D_LAT   8
#define N_CTR   64
#define CH_N    64
#define N_CLS   10

#define DT_C    0.1f
#define EPS_C   1e-4f
#define PM_STEPS 4
#define TAU_C   0.9f
#define MGAIN   0.1f
#define EIG     0.06f
#define PLR_C   0.001f
#define T_STEPS 5

#define KP      832   // 784 padded to 13*64

typedef short bf16x8 __attribute__((ext_vector_type(8)));
typedef float f32x4v __attribute__((ext_vector_type(4)));

// split f32 pair -> packed bf16 hi word + lo word (truncation; lo captures residual)
__device__ __forceinline__ void split_pair(float a, float b, unsigned& hi, unsigned& lo) {
    unsigned ua = __float_as_uint(a), ub = __float_as_uint(b);
    hi = (ua >> 16) | (ub & 0xffff0000u);
    float ra = a - __uint_as_float(ua & 0xffff0000u);
    float rb = b - __uint_as_float(ub & 0xffff0000u);
    lo = (__float_as_uint(ra) >> 16) | (__float_as_uint(rb) & 0xffff0000u);
}

// ---------------- w1t: W1[784][256] f32 -> Wt_hi/Wt_lo[256][832] bf16 (zero-padded) ----------------
__global__ __launch_bounds__(256) void w1t_kernel(
    const float* __restrict__ W1, ushort* __restrict__ WtH, ushort* __restrict__ WtL)
{
    __shared__ float t[32][36];
    const int kb = blockIdx.x;          // 0..25
    const int nb = blockIdx.y;          // 0..7
    const int tid = threadIdx.x;
    {
        const int r = tid >> 3, c4 = (tid & 7) * 4;
        const int k = kb * 32 + r;
        float4 v = {0.f, 0.f, 0.f, 0.f};
        if (k < D_IN) v = *(const float4*)(W1 + (size_t)k * 256 + nb * 32 + c4);
        t[r][c4 + 0] = v.x; t[r][c4 + 1] = v.y; t[r][c4 + 2] = v.z; t[r][c4 + 3] = v.w;
    }
    __syncthreads();
    const int n = tid >> 3, kq = (tid & 7) * 4;
    float a0 = t[kq + 0][n], a1 = t[kq + 1][n], a2 = t[kq + 2][n], a3 = t[kq + 3][n];
    unsigned h0, l0, h1w, l1w;
    split_pair(a0, a1, h0, l0);
    split_pair(a2, a3, h1w, l1w);
    const size_t o = (size_t)(nb * 32 + n) * KP + kb * 32 + kq;
    uint2 hv; hv.x = h0; hv.y = h1w;
    uint2 lv; lv.x = l0; lv.y = l1w;
    *(uint2*)(WtH + o) = hv;
    *(uint2*)(WtL + o) = lv;
}

// ---------------- enc1: h1 = tanh(x @ W1 + b1), split-bf16 3-term MFMA ----------------
// BM=128, BN=64, BK=64, 4 waves, wave-tile 64x32. Simple 2-barrier loop,
// staging regs die at the barrier (round-3 spill fix). 48 KB LDS -> 3 blocks/CU.
__global__ __launch_bounds__(256, 3) void enc1_kernel(
    const float* __restrict__ x, const ushort* __restrict__ WtH,
    const ushort* __restrict__ WtL, const float* __restrict__ b1,
    float* __restrict__ h1)
{
    __shared__ alignas(16) unsigned char AhiS[16384];
    __shared__ alignas(16) unsigned char AloS[16384];
    __shared__ alignas(16) unsigned char BhiS[8192];
    __shared__ alignas(16) unsigned char BloS[8192];

    const int tid = threadIdx.x;
    const int bx  = blockIdx.x;
    const int n0  = (bx & 3) * 64;
    const int m0  = (bx >> 2) * 128;

    // staging maps
    const int m_s = tid >> 1, kh = tid & 1;          // A: row, 32-k half
    const int n_s = tid >> 2, kq = tid & 3;          // B: row, 16-k quarter
    const float*  xrow = x + (size_t)(m0 + m_s) * D_IN;
    const ushort* bhrow = WtH + (size_t)(n0 + n_s) * KP + kq * 16;
    const ushort* blrow = WtL + (size_t)(n0 + n_s) * KP + kq * 16;
    const unsigned offB0 = (unsigned)(n_s * 128) + (unsigned)(((2 * kq)     ^ (n_s & 7)) << 4);
    const unsigned offB1 = (unsigned)(n_s * 128) + (unsigned)(((2 * kq + 1) ^ (n_s & 7)) << 4);

    // compute maps (validated round 3)
    const int lane = tid & 63;
    const int wid  = tid >> 6;
    const int wm   = wid >> 1, wn = wid & 1;
    const int fr   = lane & 15, g = lane >> 4;
    const unsigned swz = (unsigned)((fr & 7) << 4);
    const int kgb  = g * 16;

    f32x4v acc[4][2];
    #pragma unroll
    for (int mi = 0; mi < 4; ++mi)
        #pragma unroll
        for (int ni = 0; ni < 2; ++ni) acc[mi][ni] = (f32x4v){0.f, 0.f, 0.f, 0.f};

    for (int kt = 0; kt < 13; ++kt) {
        // ---- A: load f32, split, ds_write (regs die here) ----
        const int kbase = kt * 64 + kh * 32;
        float4 av[8];
        #pragma unroll
        for (int q = 0; q < 8; ++q) {
            const int kk = kbase + q * 4;
            float4 z4 = {0.f, 0.f, 0.f, 0.f};
            av[q] = (kk < D_IN) ? *(const float4*)(xrow + kk) : z4;
        }
        #pragma unroll
        for (int q16 = 0; q16 < 4; ++q16) {
            uint4 hw, lw;
            split_pair(av[2 * q16].x,     av[2 * q16].y,     hw.x, lw.x);
            split_pair(av[2 * q16].z,     av[2 * q16].w,     hw.y, lw.y);
            split_pair(av[2 * q16 + 1].x, av[2 * q16 + 1].y, hw.z, lw.z);
            split_pair(av[2 * q16 + 1].z, av[2 * q16 + 1].w, hw.w, lw.w);
            const unsigned off = (unsigned)(m_s * 128) +
                (unsigned)((((kh * 4 + q16) ^ (m_s & 7))) << 4);
            *(uint4*)(AhiS + off) = hw;
            *(uint4*)(AloS + off) = lw;
        }
        // ---- B: pure copy (bf16 prebuilt) ----
        {
            const int ko = kt * 64;
            uint4 h0 = *(const uint4*)(bhrow + ko);
            uint4 h1v = *(const uint4*)(bhrow + ko + 8);
            uint4 l0 = *(const uint4*)(blrow + ko);
            uint4 l1v = *(const uint4*)(blrow + ko + 8);
            *(uint4*)(BhiS + offB0) = h0;
            *(uint4*)(BhiS + offB1) = h1v;
            *(uint4*)(BloS + offB0) = l0;
            *(uint4*)(BloS + offB1) = l1v;
        }
        __syncthreads();

        // ---- compute: 48 MFMA / wave ----
        #pragma unroll
        for (int ks = 0; ks < 2; ++ks) {
            const unsigned kb = (unsigned)(ks * 64 + kgb);
            bf16x8 ah[4], al[4];
            #pragma unroll
            for (int mi = 0; mi < 4; ++mi) {
                const unsigned off = (unsigned)((wm * 64 + mi * 16 + fr) * 128) + (kb ^ swz);
                ah[mi] = *(const bf16x8*)(AhiS + off);
                al[mi] = *(const bf16x8*)(AloS + off);
            }
            #pragma unroll
            for (int ni = 0; ni < 2; ++ni) {
                const unsigned offb = (unsigned)((wn * 32 + ni * 16 + fr) * 128) + (kb ^ swz);
                bf16x8 bh = *(const bf16x8*)(BhiS + offb);
                bf16x8 bl = *(const bf16x8*)(BloS + offb);
                #pragma unroll
                for (int mi = 0; mi < 4; ++mi) {
                    acc[mi][ni] = __builtin_amdgcn_mfma_f32_16x16x32_bf16(ah[mi], bh, acc[mi][ni], 0, 0, 0);
                    acc[mi][ni] = __builtin_amdgcn_mfma_f32_16x16x32_bf16(ah[mi], bl, acc[mi][ni], 0, 0, 0);
                    acc[mi][ni] = __builtin_amdgcn_mfma_f32_16x16x32_bf16(al[mi], bh, acc[mi][ni], 0, 0, 0);
                }
            }
        }
        __syncthreads();
    }

    // ---- epilogue: tanh(acc + b1) -> h1 (mapping validated round 3) ----
    #pragma unroll
    for (int ni = 0; ni < 2; ++ni) {
        const int col = n0 + wn * 32 + ni * 16 + fr;
        const float bias = b1[col];
        #pragma unroll
        for (int mi = 0; mi < 4; ++mi) {
            #pragma unroll
            for (int r = 0; r < 4; ++r) {
                const int row = m0 + wm * 64 + mi * 16 + g * 4 + r;
                h1[(size_t)row * 256 + col] = tanhf(acc[mi][ni][r] + bias);
            }
        }
    }
}

// ---------------- enc2: zT[b][d] = h1[b,:] @ W2[:,d] + b2[d] ----------------
__global__ __launch_bounds__(256) void enc2_kernel(
    const float* __restrict__ h1, const float* __restrict__ W2,
    const float* __restrict__ b2, float* __restrict__ zT)
{
    __shared__ alignas(16) float hs[32][260];
    __shared__ alignas(16) float w2t[8][260];
    const int tid = threadIdx.x;
    const int r0 = blockIdx.x * 32;
    for (int i = tid; i < D_HID * D_LAT; i += 256) {
        int k = i >> 3, d = i & 7;
        w2t[d][k] = W2[i];
    }
    #pragma unroll
    for (int i = 0; i < 8; ++i) {
        int idx = tid + i * 256;
        int rr = idx >> 6, c4 = idx & 63;
        float4 v = *(const float4*)(h1 + (size_t)(r0 + rr) * D_HID + c4 * 4);
        *(float4*)&hs[rr][c4 * 4] = v;
    }
    __syncthreads();
    const int r = tid >> 3, d = tid & 7;
    float acc = 0.f;
    #pragma unroll 8
    for (int k4 = 0; k4 < 64; ++k4) {
        float4 a = *(const float4*)&hs[r][k4 * 4];
        float4 w = *(const float4*)&w2t[d][k4 * 4];
        acc = fmaf(a.x, w.x, acc);
        acc = fmaf(a.y, w.y, acc);
        acc = fmaf(a.z, w.z, acc);
        acc = fmaf(a.w, w.w, acc);
    }
    zT[(size_t)(r0 + r) * 8 + d] = acc + b2[d];
}

// ---------------- stepA2: PM evolve + membrane + EI + fused partial reduction ----------------
// 8 lanes per batch element; block = 32 b. When !last, emits part[blk][64][10].
__global__ __launch_bounds__(256) void stepA2_kernel(
    float* __restrict__ zT, float* __restrict__ hT,
    const float* __restrict__ mu, const float* __restrict__ c,
    const float* __restrict__ Wp, const float* __restrict__ bp,
    const float* __restrict__ Wr, const float* __restrict__ br,
    float* __restrict__ part, float* __restrict__ out, int t)
{
    __shared__ alignas(16) float mu_s[64];
    __shared__ alignas(16) float c_s[512];
    __shared__ alignas(16) float wp_s[512];
    __shared__ alignas(16) float bp_s[64];
    __shared__ alignas(16) float wr_s[704];
    __shared__ alignas(16) float br_s[16];
    __shared__ alignas(16) float act_s[32 * 72];   // [g][n], pad 72 -> 2-way (free)
    __shared__ alignas(16) float z_s[256];         // [g][d] == tid-linear
    __shared__ alignas(16) float post_s[32];
    __shared__ alignas(16) float red2[4 * 64 * 10];
    const int tid = threadIdx.x;
    if (tid < 64) { mu_s[tid] = mu[tid]; bp_s[tid] = bp[tid]; }
    for (int i = tid; i < 512; i += 256) { c_s[i] = c[i]; wp_s[i] = Wp[i]; }
    const bool last = (t == T_STEPS - 1);
    if (last) {
        for (int i = tid; i < 640; i += 256) wr_s[(i / 10) * 11 + (i % 10)] = Wr[i];
        if (tid < N_CLS) br_s[tid] = br[tid];
    }
    __syncthreads();

    const int sub  = tid & 7;
    const int grp  = tid >> 3;                 // 0..31, b-group within block
    const int b    = blockIdx.x * 32 + grp;
    const int lane = tid & 63;
    const int gbase = lane & ~7;

    float zown = zT[(size_t)b * 8 + sub];
    float z[8];
    #pragma unroll
    for (int d = 0; d < 8; ++d) z[d] = __shfl(zown, gbase + d, 64);

    #pragma unroll 1
    for (int it = 0; it < PM_STEPS; ++it) {
        float f[8];
        #pragma unroll
        for (int d = 0; d < 8; ++d) f[d] = 0.f;
        #pragma unroll
        for (int k = 0; k < 8; ++k) {
            const int n = sub + 8 * k;
            float dx[8];
            float r2 = EPS_C;
            #pragma unroll
            for (int d = 0; d < 8; ++d) {
                dx[d] = c_s[n * 8 + d] - z[d];
                r2 = fmaf(dx[d], dx[d], r2);
            }
            float w = mu_s[n] / r2;
            #pragma unroll
            for (int d = 0; d < 8; ++d) f[d] = fmaf(w, dx[d], f[d]);
        }
        #pragma unroll
        for (int m = 1; m <= 4; m <<= 1)
            #pragma unroll
            for (int d = 0; d < 8; ++d) f[d] += __shfl_xor(f[d], m, 64);
        #pragma unroll
        for (int d = 0; d < 8; ++d) z[d] = fmaf(DT_C, f[d], z[d]);
    }
    float zsel = z[0];
    #pragma unroll
    for (int d = 1; d < 8; ++d) if (sub == d) zsel = z[d];
    zT[(size_t)b * 8 + sub] = zsel;

    float hn[8];
    float s = 0.f;
    #pragma unroll
    for (int j = 0; j < 8; ++j) {
        const int ch = sub * 8 + j;
        float a = bp_s[ch];
        #pragma unroll
        for (int d = 0; d < 8; ++d) a = fmaf(z[d], wp_s[d * 64 + ch], a);
        hn[j] = tanhf(a);
    }
    if (t == 0) {
        #pragma unroll
        for (int j = 0; j < 8; ++j) { hn[j] = MGAIN * hn[j]; s += hn[j]; }
    } else {
        const float4* hp = (const float4*)(hT + (size_t)b * 64 + sub * 8);
        float4 h0 = hp[0], h1v = hp[1];
        hn[0] = TAU_C * h0.x + MGAIN * hn[0];
        hn[1] = TAU_C * h0.y + MGAIN * hn[1];
        hn[2] = TAU_C * h0.z + MGAIN * hn[2];
        hn[3] = TAU_C * h0.w + MGAIN * hn[3];
        hn[4] = TAU_C * h1v.x + MGAIN * hn[4];
        hn[5] = TAU_C * h1v.y + MGAIN * hn[5];
        hn[6] = TAU_C * h1v.z + MGAIN * hn[6];
        hn[7] = TAU_C * h1v.w + MGAIN * hn[7];
        #pragma unroll
        for (int j = 0; j < 8; ++j) s += hn[j];
    }
    #pragma unroll
    for (int m = 1; m <= 4; m <<= 1) s += __shfl_xor(s, m, 64);
    const float mean = s * (1.f / 64.f);
    float spost = 0.f;
    #pragma unroll
    for (int j = 0; j < 8; ++j) {
        hn[j] = hn[j] + EIG * (hn[j] - mean);
        spost += hn[j];
    }
    {
        float4 a0 = {hn[0], hn[1], hn[2], hn[3]};
        float4 a1 = {hn[4], hn[5], hn[6], hn[7]};
        float4* hp = (float4*)(hT + (size_t)b * 64 + sub * 8);
        hp[0] = a0; hp[1] = a1;
    }
    #pragma unroll
    for (int m = 1; m <= 4; m <<= 1) spost += __shfl_xor(spost, m, 64);

    if (!last) {
        // stage act / z / post into LDS, then deterministic in-block reduce
        z_s[tid] = zsel;
        if (sub == 0) post_s[grp] = spost * (1.f / 64.f);
        #pragma unroll
        for (int k = 0; k < 8; ++k) {
            const int n = sub + 8 * k;
            float r2 = 0.f;
            #pragma unroll
            for (int d = 0; d < 8; ++d) {
                float dd = c_s[n * 8 + d] - z[d];
                r2 = fmaf(dd, dd, r2);
            }
            act_s[grp * 72 + n] = expf(-r2);
        }
        __syncthreads();
        const int q = tid >> 6, n2 = tid & 63;
        float r[10];
        #pragma unroll
        for (int j = 0; j < 10; ++j) r[j] = 0.f;
        #pragma unroll
        for (int i = 0; i < 8; ++i) {
            const int g2 = q * 8 + i;
            float a = act_s[g2 * 72 + n2];
            r[0] += a;
            r[1] = fmaf(a, post_s[g2], r[1]);
            #pragma unroll
            for (int d = 0; d < 8; ++d)
                r[2 + d] = fmaf(a, z_s[g2 * 8 + d], r[2 + d]);
        }
        #pragma unroll
        for (int j = 0; j < 10; ++j) red2[(q * 64 + n2) * 10 + j] = r[j];
        __syncthreads();
        if (q == 0) {
            #pragma unroll
            for (int j = 0; j < 10; ++j) {
                float sv = (red2[(n2) * 10 + j] + red2[(64 + n2) * 10 + j]) +
                           (red2[(128 + n2) * 10 + j] + red2[(192 + n2) * 10 + j]);
                part[((size_t)blockIdx.x * 64 + n2) * 10 + j] = sv;
            }
        }
    } else {
        float lg[N_CLS];
        #pragma unroll
        for (int cls = 0; cls < N_CLS; ++cls) lg[cls] = 0.f;
        #pragma unroll
        for (int j = 0; j < 8; ++j) {
            const int ch = sub * 8 + j;
            #pragma unroll
            for (int cls = 0; cls < N_CLS; ++cls)
                lg[cls] = fmaf(hn[j], wr_s[ch * 11 + cls], lg[cls]);
        }
        #pragma unroll
        for (int m = 1; m <= 4; m <<= 1)
            #pragma unroll
            for (int cls = 0; cls < N_CLS; ++cls) lg[cls] += __shfl_xor(lg[cls], m, 64);
        if (sub == 0) {
            #pragma unroll
            for (int cls = 0; cls < N_CLS; ++cls)
                out[(size_t)b * 10 + cls] = lg[cls] + br_s[cls];
        }
        out[163840 + (size_t)b * 8 + sub] = zsel;
        {
            float4 a0 = {hn[0], hn[1], hn[2], hn[3]};
            float4 a1 = {hn[4], hn[5], hn[6], hn[7]};
            float4* op = (float4*)(out + 294912 + (size_t)b * 64 + sub * 8);
            op[0] = a0; op[1] = a1;
        }
    }
}

// ---------------- stepB2: reduce 512 partials -> mu', c' ----------------
__global__ __launch_bounds__(256) void stepB2_kernel(
    const float* __restrict__ part,
    const float* __restrict__ mu_in, const float* __restrict__ c_in,
    float* __restrict__ mu_out, float* __restrict__ c_out)
{
    const int n = blockIdx.x, tid = threadIdx.x;
    __shared__ float red[256][10];
    const float* p0 = part + ((size_t)tid * 64 + n) * 10;
    const float* p1 = part + ((size_t)(tid + 256) * 64 + n) * 10;
    #pragma unroll
    for (int j = 0; j < 10; ++j) red[tid][j] = p0[j] + p1[j];
    __syncthreads();
    for (int s = 128; s > 0; s >>= 1) {
        if (tid < s) {
            #pragma unroll
            for (int j = 0; j < 10; ++j) red[tid][j] += red[tid + s][j];
        }
        __syncthreads();
    }
    if (tid == 0) {
        const float S1 = red[0][0];
        const float S2 = red[0][1] * (1.f / B_N);
        mu_out[n] = mu_in[n] + PLR_C * S2;
        const float denom = S1 + EPS_C;
        #pragma unroll
        for (int d = 0; d < 8; ++d) {
            float s3 = red[0][2 + d];
            c_out[n * 8 + d] = c_in[n * 8 + d] + PLR_C * (s3 / denom - c_in[n * 8 + d] * (S1 / denom));
        }
    }
}

extern "C" void kernel_launch(void* const* d_in, const int* in_sizes, int n_in,
                              void* d_out, int out_size, void* d_ws, size_t ws_size,
                              hipStream_t stream) {
    (void)in_sizes; (void)n_in; (void)out_size; (void)ws_size;
    const float* x   = (const float*)d_in[0];
    const float* W1  = (const float*)d_in[1];
    const float* b1  = (const float*)d_in[2];
    const float* W2  = (const float*)d_in[3];
    const float* b2  = (const float*)d_in[4];
    const float* mu0 = (const float*)d_in[5];
    const float* c0  = (const float*)d_in[6];
    const float* Wp  = (const float*)d_in[7];
    const float* bp  = (const float*)d_in[8];
    const float* Wr  = (const float*)d_in[9];
    const float* br  = (const float*)d_in[10];
    float* out = (float*)d_out;
    float* ws  = (float*)d_ws;

    // ws layout (floats). h1 (16 MB) dead after enc2; hT/part alias it.
    float* h1    = ws;                       // [B,256]      4,194,304
    float* hT    = ws;                       // [B][64]      1,048,576 (aliases h1)
    float* part  = ws + 2113536;             // [512][64][10]  327,680 (aliases h1)
    float* zT    = ws + 4194304;             // [B][8]         131,072
    float* mu_buf = ws + 4325376;            // 2 x 64
    float* c_buf  = ws + 4325504;            // 2 x 512
    ushort* WtH  = (ushort*)(ws + 4326528);  // [256][832] bf16
    ushort* WtL  = (ushort*)(ws + 4433024);  // [256][832] bf16

    w1t_kernel<<<dim3(26, 8), 256, 0, stream>>>(W1, WtH, WtL);
    enc1_kernel<<<512, 256, 0, stream>>>(x, WtH, WtL, b1, h1);
    enc2_kernel<<<512, 256, 0, stream>>>(h1, W2, b2, zT);

    const float* mu_cur = mu0;
    const float* c_cur  = c0;
    for (int t = 0; t < T_STEPS; ++t) {
        stepA2_kernel<<<512, 256, 0, stream>>>(zT, hT, mu_cur, c_cur, Wp, bp, Wr, br,
                                               part, out, t);
        if (t < T_STEPS - 1) {
            float* mo = mu_buf + (t & 1) * 64;
            float* co = c_buf  + (t & 1) * 512;
            stepB2_kernel<<<64, 256, 0, stream>>>(part, mu_cur, c_cur, mo, co);
            mu_cur = mo;
            c_cur  = co;
        }
    }
}